// Round 13
// baseline (184.804 us; speedup 1.0000x reference)
//
#include <hip/hip_runtime.h>

// CausalSelfAttention: B=4 T=2048 D=768 NH=12 DH=64, fp32 in/out, bf16 MFMA compute.
// v13: GEMM keeps A in LDS (2 slots x 8KB, counted-vmcnt pipeline) but moves B to a
// GLOBAL->REGISTER double-buffered path (W panels are L2-resident and shared across
// blocks; LDS read-amplification of B was 2x and the dominant per-iter cost).
// Per iter: {B1; issue A-DMA(t+1) + 4 B-frag loads(t+1); vmcnt(5); B2; compute t}.
// Attn/cvt = v9 exact (best measured total).

#define B_ 4
#define T_ 2048
#define D_ 768
#define NH_ 12
#define DH_ 64
#define M_ (B_ * T_)  // 8192

typedef __attribute__((ext_vector_type(8))) short bf16x8;    // 8 bf16 = 4 VGPRs
typedef __attribute__((ext_vector_type(4))) float f32x4;
typedef __attribute__((ext_vector_type(16))) float f32x16;
typedef __attribute__((ext_vector_type(4))) unsigned int u32x4;

__device__ __forceinline__ unsigned short f2bf(float f) {
  unsigned int u = __builtin_bit_cast(unsigned int, f);
  u += 0x7FFFu + ((u >> 16) & 1u);  // RNE
  return (unsigned short)(u >> 16);
}

__device__ __forceinline__ void async16(const void* g, void* l) {
  // global->LDS DMA, 16B/lane; LDS dest = wave-uniform base + lane*16 (m97/m104)
  __builtin_amdgcn_global_load_lds(
      (const __attribute__((address_space(1))) unsigned int*)g,
      (__attribute__((address_space(3))) unsigned int*)l, 16, 0, 0);
}

// raw barrier with compiler-level memory fence (no vmcnt drain, unlike __syncthreads)
#define RAW_BARRIER()                         \
  do {                                        \
    asm volatile("" ::: "memory");            \
    __builtin_amdgcn_s_barrier();             \
    asm volatile("" ::: "memory");            \
  } while (0)

// ---------------------------------------------------------------- cvt fp32->bf16
__global__ void cvt_kernel(const float* __restrict__ x, const float* __restrict__ wq,
                           const float* __restrict__ wk, const float* __restrict__ wv,
                           const float* __restrict__ wo,
                           unsigned short* __restrict__ xb, unsigned short* __restrict__ wqb,
                           unsigned short* __restrict__ wkb, unsigned short* __restrict__ wvb,
                           unsigned short* __restrict__ wob) {
  const float* src; unsigned short* dst; int n4;
  switch (blockIdx.y) {
    case 0: src = x;  dst = xb;  n4 = M_ * D_ / 4; break;
    case 1: src = wq; dst = wqb; n4 = D_ * D_ / 4; break;
    case 2: src = wk; dst = wkb; n4 = D_ * D_ / 4; break;
    case 3: src = wv; dst = wvb; n4 = D_ * D_ / 4; break;
    default: src = wo; dst = wob; n4 = D_ * D_ / 4; break;
  }
  int stride = gridDim.x * blockDim.x;
  for (int i = blockIdx.x * blockDim.x + threadIdx.x; i < n4; i += stride) {
    float4 v = ((const float4*)src)[i];
    ushort4 o;
    o.x = f2bf(v.x); o.y = f2bf(v.y); o.z = f2bf(v.z); o.w = f2bf(v.w);
    ((ushort4*)dst)[i] = o;
  }
}

// ---------------------------------------------------------------- bf16 GEMM (B^T input)
// C[m][n] = (sum_k A[m][k]*W[n][k] + bias[n]) * scale.  128x256 tile, BK=32, 8 waves
// (wm=wid>>2: 64-row half, wn=wid&3: 64-col quarter; per-wave 64x64 out).
// A: LDS, 2 slots x 8KB, 64B rows, swizzle byte^=((row>>1)&3)<<4 via pre-swizzled
// global source (proven 0-conflict). B: GLOBAL->REG, per-lane 16B fragment loads,
// register double-buffer, 1-iter prefetch (W panel is L2-resident, 64-block reuse).
// vmcnt(5) = exactly the previous {1 A-DMA + 4 B-loads} group (in-order count, m135).
// qkv=1: grid 576 = 8 xcd x (8 mg x 9 nt); nt 0-2 Q, 3-5 K, 6-8 V(V^T out).
// qkv=0: grid 192, fp32 out.
__global__ __launch_bounds__(512) void gemm_kernel(
    const unsigned short* __restrict__ A,
    const unsigned short* __restrict__ W0, const unsigned short* __restrict__ W1,
    const unsigned short* __restrict__ W2,
    const float* __restrict__ bias0, const float* __restrict__ bias1,
    const float* __restrict__ bias2,
    void* out0, void* out1, void* out2,
    float s0, int K, int qkv) {
  __shared__ __align__(16) char lds[16384];   // A only: 2 slots x 8KB

  int bid = blockIdx.x;
  int xcd = bid & 7, g = bid >> 3;
  int mt, nt;
  if (qkv) { mt = xcd + (g / 9) * 8; nt = g % 9; }
  else     { mt = xcd + (g / 3) * 8; nt = g % 3; }
  int y  = qkv ? nt / 3 : 0;
  int nW = qkv ? nt % 3 : nt;            // 256-col tile within the 768-wide region
  const unsigned short* W = y == 0 ? W0 : (y == 1 ? W1 : W2);
  const float* bias = y == 0 ? bias0 : (y == 1 ? bias1 : bias2);
  void* outp = y == 0 ? out0 : (y == 1 ? out1 : out2);
  float scl = (qkv && y == 0) ? s0 : 1.0f;
  int mode = qkv ? ((y == 2) ? 2 : 1) : 0;

  int tid = threadIdx.x, lane = tid & 63, wid = tid >> 6;
  int l15 = lane & 15, l4 = lane >> 4;
  int wm = wid >> 2, wn = wid & 3;
  int m0 = mt << 7, n0w = nW << 8;       // n0w in [0,768)

  // A staging (per-lane global col pre-swizzled; LDS dest linear): wave wid owns
  // chunk wid (rows wid*16..+15) of the 128x32 tile (8KB).
  int aRow, aCol;
  {
    int row = wid * 16 + (lane >> 2);
    int colE = (lane & 3) * 8;
    aRow = row;
    aCol = colE ^ (((row >> 1) & 3) << 3);
  }
  // A fragment read offsets (bytes) within one slot
  int aoff[4];
#pragma unroll
  for (int mf = 0; mf < 4; ++mf) {
    int row = wm * 64 + mf * 16 + l15;
    aoff[mf] = row * 64 + ((l4 * 16) ^ (((row >> 1) & 3) << 4));
  }

  // B per-lane fragment base: row = n0w + wn*64 + nf*16 + l15, col = kt + l4*8
  const unsigned short* Wfrag = W + (size_t)(n0w + wn * 64 + l15) * K + l4 * 8;
  const size_t nstep = (size_t)16 * K;   // nf stride in elements

#define ISSUE_A(kt, slot) \
  async16(A + (size_t)(m0 + aRow) * K + (kt) + aCol, (slot) + wid * 1024)

  f32x4 acc[4][4] = {};
  char* slot0 = lds;
  char* slot1 = lds + 8192;
  bf16x8 bA[4], bB[4];

  // prologue: tile 0 -> slot0 + B(0) -> bA   (5 VMEM ops)
  ISSUE_A(0, slot0);
#pragma unroll
  for (int nf = 0; nf < 4; ++nf)
    bA[nf] = *(const bf16x8*)(Wfrag + nf * nstep);

  int NT = K >> 5;   // 24

#define STEP(t, CUR, NXT, BCUR, BNXT)                                              \
  do {                                                                             \
    RAW_BARRIER(); /* B1: iter t-1 reads of NXT done -> slot reusable */           \
    if ((t) + 1 < NT) {                                                            \
      int kt1 = ((t) + 1) << 5;                                                    \
      ISSUE_A(kt1, NXT);                                                           \
      _Pragma("unroll") for (int nf = 0; nf < 4; ++nf)                             \
        BNXT[nf] = *(const bf16x8*)(Wfrag + nf * nstep + kt1);                     \
      asm volatile("s_waitcnt vmcnt(5)" ::: "memory"); /* t-group landed */        \
    } else {                                                                       \
      asm volatile("s_waitcnt vmcnt(0)" ::: "memory"); /* tail drain */            \
    }                                                                              \
    RAW_BARRIER(); /* B2: A(t) visible to all waves */                             \
    bf16x8 af[4];                                                                  \
    _Pragma("unroll") for (int mf = 0; mf < 4; ++mf)                               \
      af[mf] = *(const bf16x8*)((CUR) + aoff[mf]);                                 \
    __builtin_amdgcn_s_setprio(1);                                                 \
    _Pragma("unroll") for (int mf = 0; mf < 4; ++mf)                               \
      _Pragma("unroll") for (int nf = 0; nf < 4; ++nf)                             \
        acc[mf][nf] = __builtin_amdgcn_mfma_f32_16x16x32_bf16(                     \
            af[mf], BCUR[nf], acc[mf][nf], 0, 0, 0);                               \
    __builtin_amdgcn_s_setprio(0);                                                 \
  } while (0)

#pragma unroll 1
  for (int t = 0; t < NT; t += 2) {
    STEP(t, slot0, slot1, bA, bB);
    STEP(t + 1, slot1, slot0, bB, bA);
  }
#undef STEP
#undef ISSUE_A

  // epilogue (v9-proven formulas)
  if (mode == 2) {
    // V^T: out[((b*NH+h)*DH + d)*T + t], 4 consecutive t per 8B store
#pragma unroll
    for (int nf = 0; nf < 4; ++nf) {
      int colW = n0w + wn * 64 + nf * 16 + l15;   // = h*DH + d  (in [0,768))
      float bv = bias[colW];
      int h = colW >> 6, d = colW & 63;
#pragma unroll
      for (int mf = 0; mf < 4; ++mf) {
        int rbase = m0 + wm * 64 + mf * 16 + l4 * 4;   // = b*T + t
        int bb = rbase >> 11, tt = rbase & (T_ - 1);
        ushort4 o;
        o.x = f2bf(acc[mf][nf][0] + bv);
        o.y = f2bf(acc[mf][nf][1] + bv);
        o.z = f2bf(acc[mf][nf][2] + bv);
        o.w = f2bf(acc[mf][nf][3] + bv);
        *(ushort4*)((unsigned short*)outp + ((size_t)(bb * NH_ + h) * DH_ + d) * T_ + tt) = o;
      }
    }
  } else {
#pragma unroll
    for (int nf = 0; nf < 4; ++nf) {
      int colW = n0w + wn * 64 + nf * 16 + l15;
      float bv = bias[colW];
#pragma unroll
      for (int mf = 0; mf < 4; ++mf) {
        int rbase = m0 + wm * 64 + mf * 16 + l4 * 4;
#pragma unroll
        for (int r = 0; r < 4; ++r) {
          float v = (acc[mf][nf][r] + bv) * scl;
          size_t idx = (size_t)(rbase + r) * D_ + colW;
          if (mode == 1) ((unsigned short*)outp)[idx] = f2bf(v);
          else           ((float*)outp)[idx] = v;
        }
      }
    }
  }
}

// ---------------------------------------------------------------- flash attention (v9)
// Block = one q-tile of 128 rows; 4 waves x 32 q-rows; 32x32x16 bf16 MFMA.
// Swapped QK^T (S^T = mfma(K,Q)); raw-exp2 softmax (Q prescaled by 0.125*log2e);
// P in registers via v_cvt_pk_bf16_f32 + v_permlane32_swap_b32. K/V dbuf in LDS;
// 1 barrier/tile; prefetch after barrier. Desc-qt LPT grid, 2 blocks/CU.
__global__ __launch_bounds__(256, 2) void attn_kernel(
    const unsigned short* __restrict__ Q, const unsigned short* __restrict__ Kg,
    const unsigned short* __restrict__ VT, unsigned short* __restrict__ Z) {
  __shared__ __align__(16) char lds[57344];  // 32KB used; padded to cap 2 blocks/CU

  int tid = threadIdx.x, lane = tid & 63, w = tid >> 6;
  int l31 = lane & 31, hi = lane >> 5;
  int bid = blockIdx.x;
  int xcd = bid & 7, g = bid >> 3;       // per XCD: 96 blocks = 16 qt x 6 heads
  int qt = 15 - g / 6;                   // descending qt: big blocks dispatch first (LPT)
  int bh = xcd + (g % 6) * 8;
  int b = bh / NH_, h = bh % NH_;
  int q0 = qt * 128;
  int qrow = q0 + w * 32 + l31;

  const unsigned short* Qb = Q + (size_t)(b * T_) * D_ + h * DH_;
  const unsigned short* Kb = Kg + (size_t)(b * T_) * D_ + h * DH_;
  const unsigned short* VTb = VT + (size_t)(b * NH_ + h) * DH_ * T_;

  // Q B-frags: qf[s] holds Q[qrow][16s + 8hi .. +8)
  bf16x8 qf[4];
#pragma unroll
  for (int s = 0; s < 4; ++s)
    qf[s] = *(const bf16x8*)(Qb + (size_t)qrow * D_ + s * 16 + hi * 8);

  // staging geometry (per-lane global source pre-swizzled; LDS dest linear)
  int sRow[2], sCol[2];
#pragma unroll
  for (int c = 0; c < 2; ++c) {
    int pos = ((c * 4 + w) * 64 + lane) * 8;
    int row = pos >> 6, colE = pos & 63;
    sRow[c] = row;
    sCol[c] = colE ^ ((row & 7) << 3);
  }

  // K/V fragment offsets within one 8KB buffer: half n/dt (32 rows), k-slice s (16)
  int koff[2][4];
#pragma unroll
  for (int n = 0; n < 2; ++n)
#pragma unroll
    for (int s = 0; s < 4; ++s) {
      int row = n * 32 + l31;
      koff[n][s] = row * 128 + ((s * 32 + hi * 16) ^ ((row & 7) << 4));
    }

  f32x16 zt[2] = {};
  float l_run = 0.f;
  int ntiles = 2 * qt + 2;

  // prologue: stage tile 0 -> K0/V0
#pragma unroll
  for (int c = 0; c < 2; ++c) {
    async16(Kb + (size_t)sRow[c] * D_ + sCol[c], lds + 0 + (c * 4 + w) * 1024);
    async16(VTb + (size_t)sRow[c] * T_ + sCol[c], lds + 16384 + (c * 4 + w) * 1024);
  }

#define ATTN_TILE(KCUR, VCUR, KNXT, VNXT)                                              \
  do {                                                                                 \
    __syncthreads(); /* drains tile-t DMAs; closes reads of the nxt buffers */         \
    if (t + 1 < ntiles) {                                                              \
      int kv1 = (t + 1) * 64;                                                          \
      _Pragma("unroll") for (int c = 0; c < 2; ++c) {                                  \
        async16(Kb + (size_t)(kv1 + sRow[c]) * D_ + sCol[c],                           \
                lds + KNXT + (c * 4 + w) * 1024);                                      \
        async16(VTb + (size_t)sRow[c] * T_ + kv1 + sCol[c],                            \
                lds + VNXT + (c * 4 + w) * 1024);                                      \
      }                                                                                \
    }                                                                                  \
    f32x16 st[2];                                                                      \
    __builtin_amdgcn_s_setprio(1);                                                     \
    _Pragma("unroll") for (int n = 0; n < 2; ++n) {                                    \
      f32x16 a = {};                                                                   \
      _Pragma("unroll") for (int s = 0; s < 4; ++s) {                                  \
        bf16x8 kf = *(const bf16x8*)(lds + KCUR + koff[n][s]);                         \
        a = __builtin_amdgcn_mfma_f32_32x32x16_bf16(kf, qf[s], a, 0, 0, 0);            \
      }                                                                                \
      st[n] = a;                                                                       \
    }                                                                                  \
    __builtin_amdgcn_s_setprio(0);                                                     \
    if (t >= 2 * qt) { /* diagonal region: mask kv > qrow */                           \
      int kvb = t * 64;                                                                \
      _Pragma("unroll") for (int n = 0; n < 2; ++n)                                    \
        _Pragma("unroll") for (int m = 0; m < 4; ++m)                                  \
          _Pragma("unroll") for (int c2 = 0; c2 < 4; ++c2) {                           \
            int kv = kvb + n * 32 + m * 8 + hi * 4 + c2;                               \
            if (kv > qrow) st[n][m * 4 + c2] = -1e30f;                                 \
          }                                                                            \
    }                                                                                  \
    bf16x8 pb[4];                                                                      \
    _Pragma("unroll") for (int n = 0; n < 2; ++n) {                                    \
      float u[16];                                                                     \
      _Pragma("unroll") for (int r = 0; r < 16; ++r) {                                 \
        u[r] = __builtin_amdgcn_exp2f(st[n][r]);                                       \
        l_run += u[r];                                                                 \
      }                                                                                \
      _Pragma("unroll") for (int hf = 0; hf < 2; ++hf) {                               \
        unsigned int A0, A1, B0, B1;                                                   \
        asm("v_cvt_pk_bf16_f32 %0, %1, %2" : "=v"(A0) : "v"(u[hf*8+0]), "v"(u[hf*8+1]));\
        asm("v_cvt_pk_bf16_f32 %0, %1, %2" : "=v"(A1) : "v"(u[hf*8+2]), "v"(u[hf*8+3]));\
        asm("v_cvt_pk_bf16_f32 %0, %1, %2" : "=v"(B0) : "v"(u[hf*8+4]), "v"(u[hf*8+5]));\
        asm("v_cvt_pk_bf16_f32 %0, %1, %2" : "=v"(B1) : "v"(u[hf*8+6]), "v"(u[hf*8+7]));\
        asm("v_permlane32_swap_b32 %0, %1" : "+v"(A0), "+v"(B0));                      \
        asm("v_permlane32_swap_b32 %0, %1" : "+v"(A1), "+v"(B1));                      \
        u32x4 pk; pk[0] = A0; pk[1] = A1; pk[2] = B0; pk[3] = B1;                      \
        pb[n * 2 + hf] = __builtin_bit_cast(bf16x8, pk);                               \
      }                                                                                \
    }                                                                                  \
    __builtin_amdgcn_s_setprio(1);                                                     \
    _Pragma("unroll") for (int dt = 0; dt < 2; ++dt) {                                 \
      _Pragma("unroll") for (int s = 0; s < 4; ++s) {                                  \
        bf16x8 vf = *(const bf16x8*)(lds + VCUR + koff[dt][s]);                        \
        zt[dt] = __builtin_amdgcn_mfma_f32_32x32x16_bf16(vf, pb[s], zt[dt], 0, 0, 0);  \
      }                                                                                \
    }                                                                                  \
    __builtin_amdgcn_s_setprio(0);                                                     \
  } while (0)

#pragma unroll 1
  for (int t = 0; t < ntiles; ++t) {
    if ((t & 1) == 0) {
      ATTN_TILE(0, 16384, 8192, 24576);
    } else {
      ATTN_TILE(8192, 24576, 0, 16384);
    }
  }
#undef ATTN_TILE

  // epilogue
  l_run += __shfl_xor(l_run, 32);
  float inv = __builtin_amdgcn_rcpf(l_run);
  unsigned short* Zrow = Z + (size_t)(b * T_ + qrow) * D_ + h * DH_;
#pragma unroll
  for (int dt = 0; dt < 2; ++dt)
#pragma unroll
    for (int m = 0; m < 4; ++m) {
      ushort4 o;
      o.x = f2bf(zt[dt][m * 4 + 0] * inv);
      o.y = f2bf(zt[dt][m * 4 + 1] * inv);
      o.z = f2bf(zt[dt][m * 4 + 2] * inv);
      o.w = f2bf(zt[dt][m * 4 + 3] * inv);
      *(ushort4*)(Zrow + dt * 32 + m * 8 + hi * 4) = o;  // d = 32dt + 8m + 4hi + c
    }
}

// ---------------------------------------------------------------- launcher
extern "C" void kernel_launch(void* const* d_in, const int* in_sizes, int n_in,
                              void* d_out, int out_size, void* d_ws, size_t ws_size,
                              hipStream_t stream) {
  (void)in_sizes; (void)n_in; (void)out_size; (void)ws_size;
  const float* x  = (const float*)d_in[0];
  const float* wq = (const float*)d_in[1];
  const float* bq = (const float*)d_in[2];
  const float* wk = (const float*)d_in[3];
  const float* bk = (const float*)d_in[4];
  const float* wv = (const float*)d_in[5];
  const float* bv = (const float*)d_in[6];
  const float* wo = (const float*)d_in[7];
  const float* bo = (const float*)d_in[8];

  char* ws = (char*)d_ws;
  const size_t XB = (size_t)M_ * D_ * 2;   // 12.58 MB
  const size_t WB = (size_t)D_ * D_ * 2;   // 1.18 MB
  unsigned short* xb  = (unsigned short*)(ws);
  unsigned short* wqb = (unsigned short*)(ws + XB);
  unsigned short* wkb = (unsigned short*)(ws + XB + WB);
  unsigned short* wvb = (unsigned short*)(ws + XB + 2 * WB);
  unsigned short* wob = (unsigned short*)(ws + XB + 3 * WB);
  unsigned short* Qb  = (unsigned short*)(ws + XB + 4 * WB);
  unsigned short* Kb  = (unsigned short*)(ws + XB + 4 * WB + XB);
  unsigned short* VTb = (unsigned short*)(ws + XB + 4 * WB + 2 * XB);
  unsigned short* Zb  = xb;  // alias: x dead after projections

  const float SCALE_Q = 0.125f * 1.44269504f;  // fold 1/sqrt(64) and log2(e) into Q

  cvt_kernel<<<dim3(1024, 5), 256, 0, stream>>>(x, wq, wk, wv, wo, xb, wqb, wkb, wvb, wob);
  // fused QKV projections (N=2304 as 9 x 256-col tiles); Q prescaled; V writes V^T.
  gemm_kernel<<<dim3(576), 512, 0, stream>>>(
      xb, wqb, wkb, wvb, bq, bk, bv, Qb, Kb, VTb, SCALE_Q, D_, 1);
  // attn: 768 blocks = 48 heads x 16 q-tiles (q=128 each), desc-qt within XCD
  attn_kernel<<<dim3(768), 256, 0, stream>>>(Qb, Kb, VTb, Zb);
  // out projection -> fp32 d_out. grid 192.
  gemm_kernel<<<dim3(192), 512, 0, stream>>>(
      Zb, wob, wob, wob, bo, bo, bo, d_out, d_out, d_out, 1.0f, D_, 0);
}

// Round 14
// 114.749 us; speedup vs baseline: 1.6105x; 1.6105x over previous
//
#include <hip/hip_runtime.h>

// CausalSelfAttention: B=4 T=2048 D=768 NH=12 DH=64, fp32 in/out, bf16 MFMA compute.
// v14: = v9 (best, 117.1us) with ONE change: attn processes KV subtiles in PAIRS --
// 4 K + 4 V LDS buffers (64KB), {__syncthreads; stage t+2,t+3} only at even t ->
// half the barrier drains, 2-subtile DMA latency cover. Subtile math identical to v9.

#define B_ 4
#define T_ 2048
#define D_ 768
#define NH_ 12
#define DH_ 64
#define M_ (B_ * T_)  // 8192

typedef __attribute__((ext_vector_type(8))) short bf16x8;    // 8 bf16 = 4 VGPRs
typedef __attribute__((ext_vector_type(4))) float f32x4;
typedef __attribute__((ext_vector_type(16))) float f32x16;
typedef __attribute__((ext_vector_type(4))) unsigned int u32x4;

__device__ __forceinline__ unsigned short f2bf(float f) {
  unsigned int u = __builtin_bit_cast(unsigned int, f);
  u += 0x7FFFu + ((u >> 16) & 1u);  // RNE
  return (unsigned short)(u >> 16);
}

__device__ __forceinline__ void async16(const void* g, void* l) {
  // global->LDS DMA, 16B/lane; LDS dest = wave-uniform base + lane*16 (m97/m104)
  __builtin_amdgcn_global_load_lds(
      (const __attribute__((address_space(1))) unsigned int*)g,
      (__attribute__((address_space(3))) unsigned int*)l, 16, 0, 0);
}

// raw barrier with compiler-level memory fence (no vmcnt drain, unlike __syncthreads)
#define RAW_BARRIER()                         \
  do {                                        \
    asm volatile("" ::: "memory");            \
    __builtin_amdgcn_s_barrier();             \
    asm volatile("" ::: "memory");            \
  } while (0)

// ---------------------------------------------------------------- cvt fp32->bf16
__global__ void cvt_kernel(const float* __restrict__ x, const float* __restrict__ wq,
                           const float* __restrict__ wk, const float* __restrict__ wv,
                           const float* __restrict__ wo,
                           unsigned short* __restrict__ xb, unsigned short* __restrict__ wqb,
                           unsigned short* __restrict__ wkb, unsigned short* __restrict__ wvb,
                           unsigned short* __restrict__ wob) {
  const float* src; unsigned short* dst; int n4;
  switch (blockIdx.y) {
    case 0: src = x;  dst = xb;  n4 = M_ * D_ / 4; break;
    case 1: src = wq; dst = wqb; n4 = D_ * D_ / 4; break;
    case 2: src = wk; dst = wkb; n4 = D_ * D_ / 4; break;
    case 3: src = wv; dst = wvb; n4 = D_ * D_ / 4; break;
    default: src = wo; dst = wob; n4 = D_ * D_ / 4; break;
  }
  int stride = gridDim.x * blockDim.x;
  for (int i = blockIdx.x * blockDim.x + threadIdx.x; i < n4; i += stride) {
    float4 v = ((const float4*)src)[i];
    ushort4 o;
    o.x = f2bf(v.x); o.y = f2bf(v.y); o.z = f2bf(v.z); o.w = f2bf(v.w);
    ((ushort4*)dst)[i] = o;
  }
}

// ---------------------------------------------------------------- bf16 GEMM (B^T input)
// v9 exact: 128x256 tile, BK=32, 8 waves (wm=wid>>2, wn=wid&3; per-wave 64x64 out).
// 3 LDS slots x 24KB = 72KB; depth-2 pipeline, 1 barrier + vmcnt(3)/iter. 64B LDS
// rows, involution swizzle byte^=((row>>1)&3)<<4 via pre-swizzled global source.
// qkv=1: grid 576 = 8 xcd x (8 mg x 9 nt); nt 0-2 Q, 3-5 K, 6-8 V(V^T out).
// qkv=0: grid 192, fp32 out.
__global__ __launch_bounds__(512, 4) void gemm_kernel(
    const unsigned short* __restrict__ A,
    const unsigned short* __restrict__ W0, const unsigned short* __restrict__ W1,
    const unsigned short* __restrict__ W2,
    const float* __restrict__ bias0, const float* __restrict__ bias1,
    const float* __restrict__ bias2,
    void* out0, void* out1, void* out2,
    float s0, int K, int qkv) {
  __shared__ __align__(16) char lds[73728];   // 3 slots x 24576 (A@0, B@8192)

  int bid = blockIdx.x;
  int xcd = bid & 7, g = bid >> 3;
  int mt, nt;
  if (qkv) { mt = xcd + (g / 9) * 8; nt = g % 9; }
  else     { mt = xcd + (g / 3) * 8;  nt = g % 3; }
  int y  = qkv ? nt / 3 : 0;
  int nW = qkv ? nt % 3 : nt;            // 256-col tile within the 768-wide region
  const unsigned short* W = y == 0 ? W0 : (y == 1 ? W1 : W2);
  const float* bias = y == 0 ? bias0 : (y == 1 ? bias1 : bias2);
  void* outp = y == 0 ? out0 : (y == 1 ? out1 : out2);
  float scl = (qkv && y == 0) ? s0 : 1.0f;
  int mode = qkv ? ((y == 2) ? 2 : 1) : 0;

  int tid = threadIdx.x, lane = tid & 63, wid = tid >> 6;
  int l15 = lane & 15, l4 = lane >> 4;
  int wm = wid >> 2, wn = wid & 3;
  int m0 = mt << 7, n0w = nW << 8;       // n0w in [0,768)

  // A: 8KB = 8 chunks of 1KB; wave wid owns chunk wid
  int aRow, aCol;
  {
    int row = wid * 16 + (lane >> 2);
    int colE = (lane & 3) * 8;
    aRow = row;
    aCol = colE ^ (((row >> 1) & 3) << 3);
  }
  // B: 16KB = 16 chunks of 1KB; wave owns {wid, wid+8}
  int bRow[2], bCol[2];
#pragma unroll
  for (int c = 0; c < 2; ++c) {
    int u = c * 8 + wid;
    int row = u * 16 + (lane >> 2);
    int colE = (lane & 3) * 8;
    bRow[c] = row;
    bCol[c] = colE ^ (((row >> 1) & 3) << 3);
  }

  int aoff[4], boff[4];
#pragma unroll
  for (int mf = 0; mf < 4; ++mf) {
    int row = wm * 64 + mf * 16 + l15;
    aoff[mf] = row * 64 + ((l4 * 16) ^ (((row >> 1) & 3) << 4));
  }
#pragma unroll
  for (int nf = 0; nf < 4; ++nf) {
    int row = wn * 64 + nf * 16 + l15;
    boff[nf] = 8192 + row * 64 + ((l4 * 16) ^ (((row >> 1) & 3) << 4));
  }

  const unsigned short* Wb = W + (size_t)n0w * K;   // 256-row W panel

#define ISSUE_TILE(kt, slot)                                                       \
  do {                                                                             \
    async16(A + (size_t)(m0 + aRow) * K + (kt) + aCol, (slot) + wid * 1024);       \
    _Pragma("unroll") for (int c = 0; c < 2; ++c)                                  \
      async16(Wb + (size_t)bRow[c] * K + (kt) + bCol[c],                           \
              (slot) + 8192 + (c * 8 + wid) * 1024);                               \
  } while (0)

  f32x4 acc[4][4] = {};
  char* b0 = lds;             // compute slot (tile t)
  char* b1 = lds + 24576;     // tile t+1 (in flight)
  char* b2 = lds + 49152;     // issue target (tile t+2)

  ISSUE_TILE(0, b0);
  ISSUE_TILE(32, b1);

  int NT = K >> 5;   // 24
#pragma unroll 1
  for (int t = 0; t < NT; ++t) {
    if (t + 1 < NT) asm volatile("s_waitcnt vmcnt(3)" ::: "memory");  // tile t landed
    else            asm volatile("s_waitcnt vmcnt(0)" ::: "memory");  // tail drain
    RAW_BARRIER();   // all waves: tile t visible; slot b2 (tile t-1) free
    if (t + 2 < NT) ISSUE_TILE((t + 2) << 5, b2);
    bf16x8 af[4], bfr[4];
#pragma unroll
    for (int mf = 0; mf < 4; ++mf) af[mf] = *(const bf16x8*)(b0 + aoff[mf]);
#pragma unroll
    for (int nf = 0; nf < 4; ++nf) bfr[nf] = *(const bf16x8*)(b0 + boff[nf]);
    __builtin_amdgcn_s_setprio(1);
#pragma unroll
    for (int mf = 0; mf < 4; ++mf)
#pragma unroll
      for (int nf = 0; nf < 4; ++nf)
        acc[mf][nf] = __builtin_amdgcn_mfma_f32_16x16x32_bf16(af[mf], bfr[nf], acc[mf][nf], 0, 0, 0);
    __builtin_amdgcn_s_setprio(0);
    char* tmp = b0; b0 = b1; b1 = b2; b2 = tmp;   // rotate slots
  }
#undef ISSUE_TILE

  // epilogue
  if (mode == 2) {
#pragma unroll
    for (int nf = 0; nf < 4; ++nf) {
      int colW = n0w + wn * 64 + nf * 16 + l15;   // = h*DH + d
      float bv = bias[colW];
      int h = colW >> 6, d = colW & 63;
#pragma unroll
      for (int mf = 0; mf < 4; ++mf) {
        int rbase = m0 + wm * 64 + mf * 16 + l4 * 4;   // = b*T + t
        int bb = rbase >> 11, tt = rbase & (T_ - 1);
        ushort4 o;
        o.x = f2bf(acc[mf][nf][0] + bv);
        o.y = f2bf(acc[mf][nf][1] + bv);
        o.z = f2bf(acc[mf][nf][2] + bv);
        o.w = f2bf(acc[mf][nf][3] + bv);
        *(ushort4*)((unsigned short*)outp + ((size_t)(bb * NH_ + h) * DH_ + d) * T_ + tt) = o;
      }
    }
  } else {
#pragma unroll
    for (int nf = 0; nf < 4; ++nf) {
      int colW = n0w + wn * 64 + nf * 16 + l15;
      float bv = bias[colW];
#pragma unroll
      for (int mf = 0; mf < 4; ++mf) {
        int rbase = m0 + wm * 64 + mf * 16 + l4 * 4;
#pragma unroll
        for (int r = 0; r < 4; ++r) {
          float v = (acc[mf][nf][r] + bv) * scl;
          size_t idx = (size_t)(rbase + r) * D_ + colW;
          if (mode == 1) ((unsigned short*)outp)[idx] = f2bf(v);
          else           ((float*)outp)[idx] = v;
        }
      }
    }
  }
}

// ---------------------------------------------------------------- flash attention v14
// = v9 structure (q=128/block, 4 waves x 32 q, 32x32x16 MFMA, swapped QK^T, raw-exp2,
// P in registers) with KV subtiles processed in PAIRS: 4 K buffers @ (t&3)*8192 and
// 4 V buffers @ 32768+(t&3)*8192 (64KB LDS, 2 blocks/CU); {__syncthreads; stage
// t+2,t+3} only at even t. Subtile math identical to v9 (mask cond t>=2*qt covers
// both subtiles of the diagonal 128-pair).
__global__ __launch_bounds__(256, 2) void attn_kernel(
    const unsigned short* __restrict__ Q, const unsigned short* __restrict__ Kg,
    const unsigned short* __restrict__ VT, unsigned short* __restrict__ Z) {
  __shared__ __align__(16) char lds[65536];

  int tid = threadIdx.x, lane = tid & 63, w = tid >> 6;
  int l31 = lane & 31, hi = lane >> 5;
  int bid = blockIdx.x;
  int xcd = bid & 7, g = bid >> 3;       // per XCD: 96 blocks = 16 qt x 6 heads
  int qt = 15 - g / 6;                   // descending qt: big blocks dispatch first (LPT)
  int bh = xcd + (g % 6) * 8;
  int b = bh / NH_, h = bh % NH_;
  int q0 = qt * 128;
  int qrow = q0 + w * 32 + l31;

  const unsigned short* Qb = Q + (size_t)(b * T_) * D_ + h * DH_;
  const unsigned short* Kb = Kg + (size_t)(b * T_) * D_ + h * DH_;
  const unsigned short* VTb = VT + (size_t)(b * NH_ + h) * DH_ * T_;

  // Q B-frags: qf[s] holds Q[qrow][16s + 8hi .. +8)
  bf16x8 qf[4];
#pragma unroll
  for (int s = 0; s < 4; ++s)
    qf[s] = *(const bf16x8*)(Qb + (size_t)qrow * D_ + s * 16 + hi * 8);

  // staging geometry (per-lane global source pre-swizzled; LDS dest linear)
  int sRow[2], sCol[2];
#pragma unroll
  for (int c = 0; c < 2; ++c) {
    int pos = ((c * 4 + w) * 64 + lane) * 8;
    int row = pos >> 6, colE = pos & 63;
    sRow[c] = row;
    sCol[c] = colE ^ ((row & 7) << 3);
  }

  // K/V fragment offsets within one 8KB buffer: half n/dt (32 rows), k-slice s (16)
  int koff[2][4];
#pragma unroll
  for (int n = 0; n < 2; ++n)
#pragma unroll
    for (int s = 0; s < 4; ++s) {
      int row = n * 32 + l31;
      koff[n][s] = row * 128 + ((s * 32 + hi * 16) ^ ((row & 7) << 4));
    }

  f32x16 zt[2] = {};
  float l_run = 0.f;
  int ntiles = 2 * qt + 2;   // always even

  // stage subtile tt into buffer set (tt&3)
#define STAGE(tt)                                                                  \
  do {                                                                             \
    int kv0 = (tt) * 64;                                                           \
    int kb = ((tt) & 3) << 13;                                                     \
    _Pragma("unroll") for (int c = 0; c < 2; ++c) {                                \
      async16(Kb + (size_t)(kv0 + sRow[c]) * D_ + sCol[c],                         \
              lds + kb + (c * 4 + w) * 1024);                                      \
      async16(VTb + (size_t)sRow[c] * T_ + kv0 + sCol[c],                          \
              lds + 32768 + kb + (c * 4 + w) * 1024);                              \
    }                                                                              \
  } while (0)

  // prologue: stage subtiles 0,1
  STAGE(0);
  STAGE(1);

#pragma unroll 1
  for (int t = 0; t < ntiles; ++t) {
    if ((t & 1) == 0) {
      __syncthreads();           // drains DMAs for t,t+1; closes reads of t+2,t+3 bufs
      if (t + 2 < ntiles) {
        STAGE(t + 2);
        STAGE(t + 3);
      }
    }
    const char* kbase = lds + ((t & 3) << 13);
    const char* vbase = lds + 32768 + ((t & 3) << 13);

    f32x16 st[2];
    __builtin_amdgcn_s_setprio(1);
#pragma unroll
    for (int n = 0; n < 2; ++n) {
      f32x16 a = {};
#pragma unroll
      for (int s = 0; s < 4; ++s) {
        bf16x8 kf = *(const bf16x8*)(kbase + koff[n][s]);
        a = __builtin_amdgcn_mfma_f32_32x32x16_bf16(kf, qf[s], a, 0, 0, 0);
      }
      st[n] = a;
    }
    __builtin_amdgcn_s_setprio(0);

    if (t >= 2 * qt) {  // diagonal 128-pair: mask kv > qrow
      int kvb = t * 64;
#pragma unroll
      for (int n = 0; n < 2; ++n)
#pragma unroll
        for (int m = 0; m < 4; ++m)
#pragma unroll
          for (int c2 = 0; c2 < 4; ++c2) {
            int kv = kvb + n * 32 + m * 8 + hi * 4 + c2;
            if (kv > qrow) st[n][m * 4 + c2] = -1e30f;
          }
    }

    bf16x8 pb[4];
#pragma unroll
    for (int n = 0; n < 2; ++n) {
      float u[16];
#pragma unroll
      for (int r = 0; r < 16; ++r) {
        u[r] = __builtin_amdgcn_exp2f(st[n][r]);
        l_run += u[r];
      }
#pragma unroll
      for (int hf = 0; hf < 2; ++hf) {
        unsigned int A0, A1, B0, B1;
        asm("v_cvt_pk_bf16_f32 %0, %1, %2" : "=v"(A0) : "v"(u[hf*8+0]), "v"(u[hf*8+1]));
        asm("v_cvt_pk_bf16_f32 %0, %1, %2" : "=v"(A1) : "v"(u[hf*8+2]), "v"(u[hf*8+3]));
        asm("v_cvt_pk_bf16_f32 %0, %1, %2" : "=v"(B0) : "v"(u[hf*8+4]), "v"(u[hf*8+5]));
        asm("v_cvt_pk_bf16_f32 %0, %1, %2" : "=v"(B1) : "v"(u[hf*8+6]), "v"(u[hf*8+7]));
        asm("v_permlane32_swap_b32 %0, %1" : "+v"(A0), "+v"(B0));
        asm("v_permlane32_swap_b32 %0, %1" : "+v"(A1), "+v"(B1));
        u32x4 pk; pk[0] = A0; pk[1] = A1; pk[2] = B0; pk[3] = B1;
        pb[n * 2 + hf] = __builtin_bit_cast(bf16x8, pk);
      }
    }

    __builtin_amdgcn_s_setprio(1);
#pragma unroll
    for (int dt = 0; dt < 2; ++dt) {
#pragma unroll
      for (int s = 0; s < 4; ++s) {
        bf16x8 vf = *(const bf16x8*)(vbase + koff[dt][s]);
        zt[dt] = __builtin_amdgcn_mfma_f32_32x32x16_bf16(vf, pb[s], zt[dt], 0, 0, 0);
      }
    }
    __builtin_amdgcn_s_setprio(0);
  }
#undef STAGE

  // epilogue
  l_run += __shfl_xor(l_run, 32);
  float inv = __builtin_amdgcn_rcpf(l_run);
  unsigned short* Zrow = Z + (size_t)(b * T_ + qrow) * D_ + h * DH_;
#pragma unroll
  for (int dt = 0; dt < 2; ++dt)
#pragma unroll
    for (int m = 0; m < 4; ++m) {
      ushort4 o;
      o.x = f2bf(zt[dt][m * 4 + 0] * inv);
      o.y = f2bf(zt[dt][m * 4 + 1] * inv);
      o.z = f2bf(zt[dt][m * 4 + 2] * inv);
      o.w = f2bf(zt[dt][m * 4 + 3] * inv);
      *(ushort4*)(Zrow + dt * 32 + m * 8 + hi * 4) = o;  // d = 32dt + 8m + 4hi + c
    }
}

// ---------------------------------------------------------------- launcher
extern "C" void kernel_launch(void* const* d_in, const int* in_sizes, int n_in,
                              void* d_out, int out_size, void* d_ws, size_t ws_size,
                              hipStream_t stream) {
  (void)in_sizes; (void)n_in; (void)out_size; (void)ws_size;
  const float* x  = (const float*)d_in[0];
  const float* wq = (const float*)d_in[1];
  const float* bq = (const float*)d_in[2];
  const float* wk = (const float*)d_in[3];
  const float* bk = (const float*)d_in[4];
  const float* wv = (const float*)d_in[5];
  const float* bv = (const float*)d_in[6];
  const float* wo = (const float*)d_in[7];
  const float* bo = (const float*)d_in[8];

  char* ws = (char*)d_ws;
  const size_t XB = (size_t)M_ * D_ * 2;   // 12.58 MB
  const size_t WB = (size_t)D_ * D_ * 2;   // 1.18 MB
  unsigned short* xb  = (unsigned short*)(ws);
  unsigned short* wqb = (unsigned short*)(ws + XB);
  unsigned short* wkb = (unsigned short*)(ws + XB + WB);
  unsigned short* wvb = (unsigned short*)(ws + XB + 2 * WB);
  unsigned short* wob = (unsigned short*)(ws + XB + 3 * WB);
  unsigned short* Qb  = (unsigned short*)(ws + XB + 4 * WB);
  unsigned short* Kb  = (unsigned short*)(ws + XB + 4 * WB + XB);
  unsigned short* VTb = (unsigned short*)(ws + XB + 4 * WB + 2 * XB);
  unsigned short* Zb  = xb;  // alias: x dead after projections

  const float SCALE_Q = 0.125f * 1.44269504f;  // fold 1/sqrt(64) and log2(e) into Q

  cvt_kernel<<<dim3(1024, 5), 256, 0, stream>>>(x, wq, wk, wv, wo, xb, wqb, wkb, wvb, wob);
  // fused QKV projections (N=2304 as 9 x 256-col tiles); Q prescaled; V writes V^T.
  gemm_kernel<<<dim3(576), 512, 0, stream>>>(
      xb, wqb, wkb, wvb, bq, bk, bv, Qb, Kb, VTb, SCALE_Q, D_, 1);
  // attn: 768 blocks = 48 heads x 16 q-tiles (q=128 each), desc-qt within XCD
  attn_kernel<<<dim3(768), 256, 0, stream>>>(Qb, Kb, VTb, Zb);
  // out projection -> fp32 d_out. grid 192.
  gemm_kernel<<<dim3(192), 512, 0, stream>>>(
      Zb, wob, wob, wob, bo, bo, bo, d_out, d_out, d_out, 1.0f, D_, 0);
}